// Round 1
// baseline (117.962 us; speedup 1.0000x reference)
//
#include <hip/hip_runtime.h>
#include <math.h>

// Problem constants (fixed by setup_inputs): B=2, S=2048, D=128, NH=8, NB=32
constexpr int B = 2;
constexpr int S = 2048;
constexpr int D = 128;
constexpr int NH = 8;
constexpr int NK = 16;          // num_buckets / 2
constexpr float EPS = 1e-5f;
constexpr float SCALE = 0.08838834764831845f;  // 1/sqrt(128)

// Kernel 1: LayerNorm + last-round LSH hash.
// One block per row (b,s), 128 threads (one per d).
__global__ __launch_bounds__(128) void ln_hash_kernel(
    const float* __restrict__ x, const float* __restrict__ mask,
    const float* __restrict__ rot, float* __restrict__ xm,
    int* __restrict__ bucket)
{
    const int row = blockIdx.x;          // b*S + s
    const int b = row / S;
    const int tid = threadIdx.x;         // d

    __shared__ float red[128];
    __shared__ float sx[128];
    __shared__ float srot[NK];

    const float v = x[(size_t)row * D + tid];

    // mean
    red[tid] = v;
    __syncthreads();
    for (int off = 64; off > 0; off >>= 1) {
        if (tid < off) red[tid] += red[tid + off];
        __syncthreads();
    }
    const float mu = red[0] * (1.0f / D);
    __syncthreads();

    // variance
    const float c = v - mu;
    red[tid] = c * c;
    __syncthreads();
    for (int off = 64; off > 0; off >>= 1) {
        if (tid < off) red[tid] += red[tid + off];
        __syncthreads();
    }
    const float var = red[0] * (1.0f / D);

    const float xn = c * (1.0f / sqrtf(var + EPS));
    sx[tid] = xn;
    xm[(size_t)row * D + tid] = xn * mask[row];   // xm = xn * input_mask
    __syncthreads();

    // hash projection, last round only: rot[k] = sum_d xn[d] * R[b,d,NH-1,k]
    if (tid < NK) {
        float acc = 0.0f;
        // rotations index: ((b*D + d)*NH + (NH-1))*NK + k ; stride over d = NH*NK
        const float* rp = rot + (((size_t)b * D) * NH + (NH - 1)) * NK + tid;
        for (int d = 0; d < D; ++d) acc += sx[d] * rp[(size_t)d * NH * NK];
        srot[tid] = acc;
    }
    __syncthreads();

    // argmax over [rot, -rot] (first-max semantics, matching jnp.argmax)
    if (tid == 0) {
        float best = srot[0];
        int bi = 0;
        for (int k = 1; k < NK; ++k) {
            if (srot[k] > best) { best = srot[k]; bi = k; }
        }
        for (int k = NK; k < 2 * NK; ++k) {
            const float val = -srot[k - NK];
            if (val > best) { best = val; bi = k; }
        }
        bucket[row] = bi;
    }
}

// Kernel 2: per-row bucketed attention with exact softmax semantics.
// Scores are (xm_s . xm_t)*scale for t in same bucket, 0 otherwise; softmax
// runs over all S entries -> denominator gets (S - n)*exp(-M) correction.
// One block per query row, 256 threads.
__global__ __launch_bounds__(256) void attn_kernel(
    const float* __restrict__ xm, const int* __restrict__ bucket,
    float* __restrict__ out)
{
    const int row = blockIdx.x;          // b*S + s
    const int b = row / S;
    const int tid = threadIdx.x;
    const int lane = tid & 63;
    const int wave = tid >> 6;

    __shared__ float q[D];
    __shared__ int   tl[S];
    __shared__ float w[S];
    __shared__ float red[256];
    __shared__ int   nm;

    const int beta = bucket[row];
    if (tid < D) q[tid] = xm[(size_t)row * D + tid];
    if (tid == 0) nm = 0;
    __syncthreads();

    // compact indices of same-bucket rows
    const int base = b * S;
    for (int t = tid; t < S; t += 256) {
        if (bucket[base + t] == beta) {
            const int p = atomicAdd(&nm, 1);
            tl[p] = t;
        }
    }
    __syncthreads();
    const int n = nm;   // n >= 1 (row s always matches its own bucket)

    // dots: one wave per key
    for (int i = wave; i < n; i += 4) {
        const int t = tl[i];
        const float* kp = xm + (size_t)(base + t) * D;
        float p = kp[lane] * q[lane] + kp[lane + 64] * q[lane + 64];
        for (int off = 32; off > 0; off >>= 1) p += __shfl_xor(p, off, 64);
        if (lane == 0) w[i] = p * SCALE;
    }
    __syncthreads();

    // max over scores; the S-n zero entries floor it at 0.
    // (When n == S the self-dot ||xm_s||^2*scale >= 0 keeps this exact.)
    float m = 0.0f;
    for (int i = tid; i < n; i += 256) m = fmaxf(m, w[i]);
    red[tid] = m;
    __syncthreads();
    for (int off = 128; off > 0; off >>= 1) {
        if (tid < off) red[tid] = fmaxf(red[tid], red[tid + off]);
        __syncthreads();
    }
    const float M = red[0];
    __syncthreads();

    // denominator: matched exps + (S - n) * exp(-M) from the zero scores
    float dsum = 0.0f;
    for (int i = tid; i < n; i += 256) dsum += expf(w[i] - M);
    red[tid] = dsum;
    __syncthreads();
    for (int off = 128; off > 0; off >>= 1) {
        if (tid < off) red[tid] += red[tid + off];
        __syncthreads();
    }
    const float denom = red[0] + (float)(S - n) * expf(-M);
    const float inv = 1.0f / denom;
    __syncthreads();

    for (int i = tid; i < n; i += 256) w[i] = expf(w[i] - M) * inv;
    __syncthreads();

    // output: out_d = sum_i w[i] * xm[t_i, d]; 256 threads = 2 halves x 128 dims
    const int d = tid & 127;
    const int half = tid >> 7;
    float acc = 0.0f;
    for (int i = half; i < n; i += 2)
        acc += w[i] * xm[(size_t)(base + tl[i]) * D + d];
    red[tid] = acc;
    __syncthreads();
    if (tid < 128) out[(size_t)row * D + tid] = red[tid] + red[tid + 128];
}

extern "C" void kernel_launch(void* const* d_in, const int* in_sizes, int n_in,
                              void* d_out, int out_size, void* d_ws, size_t ws_size,
                              hipStream_t stream) {
    const float* x    = (const float*)d_in[0];   // (B,S,D) fp32
    const float* mask = (const float*)d_in[1];   // (B,S) fp32
    const float* rot  = (const float*)d_in[2];   // (B,D,NH,NK) fp32
    // d_in[3] = num_buckets (32), fixed by rotations shape; unused at runtime

    float* xm    = (float*)d_ws;                                   // B*S*D floats = 2 MB
    int*   bucket = (int*)((char*)d_ws + (size_t)B * S * D * sizeof(float)); // B*S ints
    float* out   = (float*)d_out;

    ln_hash_kernel<<<B * S, 128, 0, stream>>>(x, mask, rot, xm, bucket);
    attn_kernel<<<B * S, 256, 0, stream>>>(xm, bucket, out);
}